// Round 1
// baseline (1845.550 us; speedup 1.0000x reference)
//
#include <hip/hip_runtime.h>
#include <math.h>

#define NDIM 128

__device__ __forceinline__ void atomAddF(float* p, float v) {
    // HW fp32 atomic add (global_atomic_add_f32), not a CAS loop
    unsafeAtomicAdd(p, v);
}

// ---------------------------------------------------------------------------
// K1: xt = x @ W  (f32 vector-ALU GEMM, W staged in LDS, 4x4 register tile)
//     also s1[n] = xt[n]·a1, s3[n] = xt[n]·a3  (fused row reductions)
// LDS: 64KB (W) + 16KB (x tile) = 80KB -> 2 blocks/CU
// ---------------------------------------------------------------------------
__global__ __launch_bounds__(256) void k_xt(
    const float* __restrict__ x, const float* __restrict__ W,
    const float* __restrict__ a,
    float* __restrict__ xt, float* __restrict__ s1, float* __restrict__ s3,
    int n_nodes)
{
    __shared__ float Wl[NDIM * NDIM];   // 64 KB
    __shared__ float xr[32 * NDIM];     // 16 KB

    const int tid = threadIdx.x;
    for (int i = tid * 4; i < NDIM * NDIM; i += 256 * 4)
        *reinterpret_cast<float4*>(&Wl[i]) = *reinterpret_cast<const float4*>(&W[i]);

    const int cg = tid & 31;   // column group: cols 4*cg .. 4*cg+3
    const int rg = tid >> 5;   // row group:    rows 4*rg .. 4*rg+3 (within 32-row tile)

    float av1[4], av3[4];
    #pragma unroll
    for (int j = 0; j < 4; ++j) {
        av1[j] = a[4 * cg + j];
        av3[j] = a[256 + 4 * cg + j];
    }

    const int ROWS = 128;                      // rows per block
    const int rowBase = blockIdx.x * ROWS;

    for (int it = 0; it < ROWS; it += 32) {
        const int tileBase = rowBase + it;
        __syncthreads();
        // stage 32 rows x 128 cols of x
        for (int i = tid * 4; i < 32 * NDIM; i += 256 * 4) {
            int row = tileBase + (i >> 7);
            float4 v = make_float4(0.f, 0.f, 0.f, 0.f);
            if (row < n_nodes)
                v = *reinterpret_cast<const float4*>(&x[(size_t)row * NDIM + (i & 127)]);
            *reinterpret_cast<float4*>(&xr[i]) = v;
        }
        __syncthreads();

        float acc[4][4];
        #pragma unroll
        for (int i = 0; i < 4; ++i)
            #pragma unroll
            for (int j = 0; j < 4; ++j) acc[i][j] = 0.f;

        for (int k = 0; k < NDIM; ++k) {
            float4 wv = *reinterpret_cast<const float4*>(&Wl[k * NDIM + cg * 4]);
            #pragma unroll
            for (int i = 0; i < 4; ++i) {
                float xv = xr[(4 * rg + i) * NDIM + k];
                acc[i][0] = fmaf(xv, wv.x, acc[i][0]);
                acc[i][1] = fmaf(xv, wv.y, acc[i][1]);
                acc[i][2] = fmaf(xv, wv.z, acc[i][2]);
                acc[i][3] = fmaf(xv, wv.w, acc[i][3]);
            }
        }

        float r1[4], r3[4];
        #pragma unroll
        for (int i = 0; i < 4; ++i) {
            int row = tileBase + 4 * rg + i;
            if (row < n_nodes) {
                float4 o = make_float4(acc[i][0], acc[i][1], acc[i][2], acc[i][3]);
                *reinterpret_cast<float4*>(&xt[(size_t)row * NDIM + cg * 4]) = o;
            }
            r1[i] = acc[i][0] * av1[0] + acc[i][1] * av1[1] + acc[i][2] * av1[2] + acc[i][3] * av1[3];
            r3[i] = acc[i][0] * av3[0] + acc[i][1] * av3[1] + acc[i][2] * av3[2] + acc[i][3] * av3[3];
        }
        // reduce over the 32 lanes holding this row's 128 columns
        #pragma unroll
        for (int off = 16; off; off >>= 1) {
            #pragma unroll
            for (int i = 0; i < 4; ++i) {
                r1[i] += __shfl_xor(r1[i], off);
                r3[i] += __shfl_xor(r3[i], off);
            }
        }
        if (cg == 0) {
            #pragma unroll
            for (int i = 0; i < 4; ++i) {
                int row = tileBase + 4 * rg + i;
                if (row < n_nodes) { s1[row] = r1[i]; s3[row] = r3[i]; }
            }
        }
    }
}

// ---------------------------------------------------------------------------
// K2: s2[rel] = rel_emb[rel] · (W_r @ a2)    (single tiny block)
// ---------------------------------------------------------------------------
__global__ __launch_bounds__(128) void k_rel(
    const float* __restrict__ W_r, const float* __restrict__ a,
    const float* __restrict__ rel_emb, float* __restrict__ s2)
{
    __shared__ float v[NDIM];
    const int t = threadIdx.x;           // 128 threads
    float acc = 0.f;
    for (int c = 0; c < NDIM; ++c)
        acc = fmaf(W_r[t * NDIM + c], a[128 + c], acc);
    v[t] = acc;
    __syncthreads();
    if (t < 64) {
        float s = 0.f;
        for (int k = 0; k < NDIM; ++k)
            s = fmaf(rel_emb[t * NDIM + k], v[k], s);
        s2[t] = s;
    }
}

// ---------------------------------------------------------------------------
// K3: att_exp[e] = exp(leaky_relu(s1[src]+s2[type]+s3[dst], 0.2))
//     att_sum[dst] += att_exp[e]
// (global max subtraction skipped: cancels in normalization, values <= e^~6)
// ---------------------------------------------------------------------------
__global__ __launch_bounds__(256) void k_att(
    const int* __restrict__ src, const int* __restrict__ dst,
    const int* __restrict__ etype,
    const float* __restrict__ s1, const float* __restrict__ s2,
    const float* __restrict__ s3,
    float* __restrict__ attexp, float* __restrict__ attsum, int n_edges)
{
    int e = blockIdx.x * 256 + threadIdx.x;
    if (e >= n_edges) return;
    int d = dst[e];
    float v = s1[src[e]] + s2[etype[e]] + s3[d];
    v = (v >= 0.f) ? v : 0.2f * v;
    float w = expf(v);
    attexp[e] = w;
    atomAddF(&attsum[d], w);
}

// ---------------------------------------------------------------------------
// K4: out[dst] += att_exp[e] * xt[src]   (32 lanes per edge, float4 gather)
// ---------------------------------------------------------------------------
__global__ __launch_bounds__(256) void k_scatter(
    const float* __restrict__ xt, const float* __restrict__ attexp,
    const int* __restrict__ src, const int* __restrict__ dst,
    float* __restrict__ out, int n_edges)
{
    int e = blockIdx.x * 8 + (threadIdx.x >> 5);
    if (e >= n_edges) return;
    const int lane = threadIdx.x & 31;
    const int s = src[e];
    const int d = dst[e];
    const float w = attexp[e];
    const float4 v = *reinterpret_cast<const float4*>(&xt[(size_t)s * NDIM + lane * 4]);
    float* o = &out[(size_t)d * NDIM + lane * 4];
    atomAddF(o + 0, w * v.x);
    atomAddF(o + 1, w * v.y);
    atomAddF(o + 2, w * v.z);
    atomAddF(o + 3, w * v.w);
}

// ---------------------------------------------------------------------------
// K5: out[n] /= (att_sum[n] + 1e-10)
// ---------------------------------------------------------------------------
__global__ __launch_bounds__(256) void k_norm(
    float* __restrict__ out, const float* __restrict__ attsum, int n_nodes)
{
    int idx = blockIdx.x * 256 + threadIdx.x;   // one float4 each
    int n = idx >> 5;
    int c = idx & 31;
    if (n >= n_nodes) return;
    float inv = 1.0f / (attsum[n] + 1e-10f);
    float4* p = reinterpret_cast<float4*>(out) + (size_t)n * 32 + c;
    float4 v = *p;
    v.x *= inv; v.y *= inv; v.z *= inv; v.w *= inv;
    *p = v;
}

extern "C" void kernel_launch(void* const* d_in, const int* in_sizes, int n_in,
                              void* d_out, int out_size, void* d_ws, size_t ws_size,
                              hipStream_t stream)
{
    const float* x    = (const float*)d_in[0];
    const int*   ei   = (const int*)d_in[1];   // [2,E] row-major: src then dst
    const int*   et   = (const int*)d_in[2];
    const float* W    = (const float*)d_in[3];
    const float* W_r  = (const float*)d_in[4];
    const float* a    = (const float*)d_in[5];
    const float* rel  = (const float*)d_in[6];
    float* out = (float*)d_out;

    const int E = in_sizes[2];
    const int N = in_sizes[0] / NDIM;

    float* ws     = (float*)d_ws;
    float* xt     = ws;                          // N*128
    float* attexp = xt + (size_t)N * NDIM;       // E
    float* attsum = attexp + E;                  // N
    float* s1     = attsum + N;                  // N
    float* s3     = s1 + N;                      // N
    float* s2     = s3 + N;                      // 64

    hipMemsetAsync(attsum, 0, (size_t)N * sizeof(float), stream);
    hipMemsetAsync(d_out, 0, (size_t)out_size * sizeof(float), stream);

    k_xt<<<(N + 127) / 128, 256, 0, stream>>>(x, W, a, xt, s1, s3, N);
    k_rel<<<1, 128, 0, stream>>>(W_r, a, rel, s2);
    k_att<<<(E + 255) / 256, 256, 0, stream>>>(ei, ei + E, et, s1, s2, s3, attexp, attsum, E);
    k_scatter<<<(E + 7) / 8, 256, 0, stream>>>(xt, attexp, ei, ei + E, out, E);
    k_norm<<<(N * 32 + 255) / 256, 256, 0, stream>>>(out, attsum, N);
}

// Round 2
// 325.101 us; speedup vs baseline: 5.6768x; 5.6768x over previous
//
#include <hip/hip_runtime.h>
#include <math.h>

#define NDIM 128

__device__ __forceinline__ void atomAddF(float* p, float v) {
    // HW fp32 atomic add (global_atomic_add_f32), not a CAS loop
    unsafeAtomicAdd(p, v);
}

// ---------------------------------------------------------------------------
// K1: xt = x @ W  (f32 vector-ALU GEMM, W staged in LDS, 4x4 register tile)
//     also s1[n] = xt[n]·a1, s3[n] = xt[n]·a3  (fused row reductions)
// ---------------------------------------------------------------------------
__global__ __launch_bounds__(256) void k_xt(
    const float* __restrict__ x, const float* __restrict__ W,
    const float* __restrict__ a,
    float* __restrict__ xt, float* __restrict__ s1, float* __restrict__ s3,
    int n_nodes)
{
    __shared__ float Wl[NDIM * NDIM];   // 64 KB
    __shared__ float xr[32 * NDIM];     // 16 KB

    const int tid = threadIdx.x;
    for (int i = tid * 4; i < NDIM * NDIM; i += 256 * 4)
        *reinterpret_cast<float4*>(&Wl[i]) = *reinterpret_cast<const float4*>(&W[i]);

    const int cg = tid & 31;   // column group: cols 4*cg .. 4*cg+3
    const int rg = tid >> 5;   // row group:    rows 4*rg .. 4*rg+3 (within 32-row tile)

    float av1[4], av3[4];
    #pragma unroll
    for (int j = 0; j < 4; ++j) {
        av1[j] = a[4 * cg + j];
        av3[j] = a[256 + 4 * cg + j];
    }

    const int ROWS = 128;                      // rows per block
    const int rowBase = blockIdx.x * ROWS;

    for (int it = 0; it < ROWS; it += 32) {
        const int tileBase = rowBase + it;
        __syncthreads();
        for (int i = tid * 4; i < 32 * NDIM; i += 256 * 4) {
            int row = tileBase + (i >> 7);
            float4 v = make_float4(0.f, 0.f, 0.f, 0.f);
            if (row < n_nodes)
                v = *reinterpret_cast<const float4*>(&x[(size_t)row * NDIM + (i & 127)]);
            *reinterpret_cast<float4*>(&xr[i]) = v;
        }
        __syncthreads();

        float acc[4][4];
        #pragma unroll
        for (int i = 0; i < 4; ++i)
            #pragma unroll
            for (int j = 0; j < 4; ++j) acc[i][j] = 0.f;

        for (int k = 0; k < NDIM; ++k) {
            float4 wv = *reinterpret_cast<const float4*>(&Wl[k * NDIM + cg * 4]);
            #pragma unroll
            for (int i = 0; i < 4; ++i) {
                float xv = xr[(4 * rg + i) * NDIM + k];
                acc[i][0] = fmaf(xv, wv.x, acc[i][0]);
                acc[i][1] = fmaf(xv, wv.y, acc[i][1]);
                acc[i][2] = fmaf(xv, wv.z, acc[i][2]);
                acc[i][3] = fmaf(xv, wv.w, acc[i][3]);
            }
        }

        float r1[4], r3[4];
        #pragma unroll
        for (int i = 0; i < 4; ++i) {
            int row = tileBase + 4 * rg + i;
            if (row < n_nodes) {
                float4 o = make_float4(acc[i][0], acc[i][1], acc[i][2], acc[i][3]);
                *reinterpret_cast<float4*>(&xt[(size_t)row * NDIM + cg * 4]) = o;
            }
            r1[i] = acc[i][0] * av1[0] + acc[i][1] * av1[1] + acc[i][2] * av1[2] + acc[i][3] * av1[3];
            r3[i] = acc[i][0] * av3[0] + acc[i][1] * av3[1] + acc[i][2] * av3[2] + acc[i][3] * av3[3];
        }
        #pragma unroll
        for (int off = 16; off; off >>= 1) {
            #pragma unroll
            for (int i = 0; i < 4; ++i) {
                r1[i] += __shfl_xor(r1[i], off);
                r3[i] += __shfl_xor(r3[i], off);
            }
        }
        if (cg == 0) {
            #pragma unroll
            for (int i = 0; i < 4; ++i) {
                int row = tileBase + 4 * rg + i;
                if (row < n_nodes) { s1[row] = r1[i]; s3[row] = r3[i]; }
            }
        }
    }
}

// ---------------------------------------------------------------------------
// K2: s2[rel] = rel_emb[rel] · (W_r @ a2)
// ---------------------------------------------------------------------------
__global__ __launch_bounds__(128) void k_rel(
    const float* __restrict__ W_r, const float* __restrict__ a,
    const float* __restrict__ rel_emb, float* __restrict__ s2)
{
    __shared__ float v[NDIM];
    const int t = threadIdx.x;
    float acc = 0.f;
    for (int c = 0; c < NDIM; ++c)
        acc = fmaf(W_r[t * NDIM + c], a[128 + c], acc);
    v[t] = acc;
    __syncthreads();
    if (t < 64) {
        float s = 0.f;
        for (int k = 0; k < NDIM; ++k)
            s = fmaf(rel_emb[t * NDIM + k], v[k], s);
        s2[t] = s;
    }
}

// ---------------------------------------------------------------------------
// K3: in-degree histogram
// ---------------------------------------------------------------------------
__global__ __launch_bounds__(256) void k_count(
    const int* __restrict__ dst, int* __restrict__ deg, int n_edges)
{
    int e = blockIdx.x * 256 + threadIdx.x;
    if (e < n_edges) atomicAdd(&deg[dst[e]], 1);
}

// ---------------------------------------------------------------------------
// K4a: per-block exclusive scan (1024 elems/block) + block totals
// ---------------------------------------------------------------------------
__global__ __launch_bounds__(1024) void k_scan1(
    const int* __restrict__ deg, int* __restrict__ locpre,
    int* __restrict__ btot, int n)
{
    __shared__ int sh[1024];
    const int tid = threadIdx.x;
    const int i = blockIdx.x * 1024 + tid;
    int v = (i < n) ? deg[i] : 0;
    sh[tid] = v;
    __syncthreads();
    for (int off = 1; off < 1024; off <<= 1) {
        int t = sh[tid];
        if (tid >= off) t += sh[tid - off];
        __syncthreads();
        sh[tid] = t;
        __syncthreads();
    }
    if (i < n) locpre[i] = sh[tid] - v;      // exclusive within block
    if (tid == 1023) btot[blockIdx.x] = sh[1023];
}

// K4b: exclusive scan of block totals, in place (nb ~ 98, serial is fine)
__global__ void k_scan2(int* __restrict__ bt, int nb)
{
    if (threadIdx.x == 0) {
        int s = 0;
        for (int b = 0; b < nb; ++b) { int t = bt[b]; bt[b] = s; s += t; }
    }
}

// ---------------------------------------------------------------------------
// K5: att_exp + att_sum + CSR placement (record = {src, w} packed in int2)
// ---------------------------------------------------------------------------
__global__ __launch_bounds__(256) void k_att_place(
    const int* __restrict__ src, const int* __restrict__ dst,
    const int* __restrict__ etype,
    const float* __restrict__ s1, const float* __restrict__ s2,
    const float* __restrict__ s3,
    const int* __restrict__ locpre, const int* __restrict__ bpre,
    int* __restrict__ fill, float* __restrict__ attsum,
    int2* __restrict__ rec, int n_edges)
{
    int e = blockIdx.x * 256 + threadIdx.x;
    if (e >= n_edges) return;
    const int s = src[e];
    const int d = dst[e];
    float v = s1[s] + s2[etype[e]] + s3[d];
    v = (v >= 0.f) ? v : 0.2f * v;
    const float w = expf(v);
    atomAddF(&attsum[d], w);
    const int pos = locpre[d] + bpre[d >> 10] + atomicAdd(&fill[d], 1);
    rec[pos] = make_int2(s, __float_as_int(w));
}

// ---------------------------------------------------------------------------
// K6: gather-reduce. One 64-lane wave per node; lane owns 2 columns (float2).
//     out[n] = (sum_e w_e * xt[src_e]) / (attsum[n] + 1e-10)
// ---------------------------------------------------------------------------
__global__ __launch_bounds__(256) void k_gather(
    const float* __restrict__ xt, const int2* __restrict__ rec,
    const int* __restrict__ deg, const int* __restrict__ locpre,
    const int* __restrict__ bpre, const float* __restrict__ attsum,
    float* __restrict__ out, int n_nodes)
{
    const int n = blockIdx.x * 4 + (threadIdx.x >> 6);
    if (n >= n_nodes) return;
    const int lane = threadIdx.x & 63;
    const int start = __builtin_amdgcn_readfirstlane(locpre[n] + bpre[n >> 10]);
    const int cnt   = __builtin_amdgcn_readfirstlane(deg[n]);
    const float2* __restrict__ xt2 = reinterpret_cast<const float2*>(xt);

    float2 acc = make_float2(0.f, 0.f);
    int i = 0;
    for (; i + 2 <= cnt; i += 2) {
        int2 r0 = rec[start + i];
        int2 r1 = rec[start + i + 1];
        float2 v0 = xt2[(size_t)r0.x * 64 + lane];
        float2 v1 = xt2[(size_t)r1.x * 64 + lane];
        float w0 = __int_as_float(r0.y);
        float w1 = __int_as_float(r1.y);
        acc.x = fmaf(w0, v0.x, acc.x); acc.y = fmaf(w0, v0.y, acc.y);
        acc.x = fmaf(w1, v1.x, acc.x); acc.y = fmaf(w1, v1.y, acc.y);
    }
    if (i < cnt) {
        int2 r = rec[start + i];
        float2 v = xt2[(size_t)r.x * 64 + lane];
        float w = __int_as_float(r.y);
        acc.x = fmaf(w, v.x, acc.x); acc.y = fmaf(w, v.y, acc.y);
    }
    const float inv = 1.0f / (attsum[n] + 1e-10f);
    reinterpret_cast<float2*>(out)[(size_t)n * 64 + lane] =
        make_float2(acc.x * inv, acc.y * inv);
}

extern "C" void kernel_launch(void* const* d_in, const int* in_sizes, int n_in,
                              void* d_out, int out_size, void* d_ws, size_t ws_size,
                              hipStream_t stream)
{
    const float* x    = (const float*)d_in[0];
    const int*   ei   = (const int*)d_in[1];   // [2,E]: src row then dst row
    const int*   et   = (const int*)d_in[2];
    const float* W    = (const float*)d_in[3];
    const float* W_r  = (const float*)d_in[4];
    const float* a    = (const float*)d_in[5];
    const float* rel  = (const float*)d_in[6];
    float* out = (float*)d_out;

    const int E  = in_sizes[2];
    const int N  = in_sizes[0] / NDIM;
    const int NB = (N + 1023) / 1024;

    float* ws     = (float*)d_ws;
    float* xt     = ws;                           // N*128
    float* s1     = xt + (size_t)N * NDIM;        // N
    float* s3     = s1 + N;                       // N
    float* s2     = s3 + N;                       // 64
    float* attsum = s2 + 64;                      // N
    int*   deg    = (int*)(attsum + N);           // N
    int*   locpre = deg + N;                      // N
    int*   btot   = locpre + N;                   // NB (becomes bpre after scan2)
    int*   fill   = btot + NB + (NB & 1);         // N (keep 8B alignment downstream)
    int2*  rec    = (int2*)(fill + N);            // E records (8B each)

    const int* srcArr = ei;
    const int* dstArr = ei + E;

    hipMemsetAsync(attsum, 0, (size_t)N * sizeof(float), stream);
    hipMemsetAsync(deg,    0, (size_t)N * sizeof(int),   stream);
    hipMemsetAsync(fill,   0, (size_t)N * sizeof(int),   stream);

    k_xt<<<(N + 127) / 128, 256, 0, stream>>>(x, W, a, xt, s1, s3, N);
    k_rel<<<1, 128, 0, stream>>>(W_r, a, rel, s2);
    k_count<<<(E + 255) / 256, 256, 0, stream>>>(dstArr, deg, E);
    k_scan1<<<NB, 1024, 0, stream>>>(deg, locpre, btot, N);
    k_scan2<<<1, 64, 0, stream>>>(btot, NB);
    k_att_place<<<(E + 255) / 256, 256, 0, stream>>>(
        srcArr, dstArr, et, s1, s2, s3, locpre, btot, fill, attsum, rec, E);
    k_gather<<<(N + 3) / 4, 256, 0, stream>>>(
        xt, rec, deg, locpre, btot, attsum, out, N);
}

// Round 3
// 237.807 us; speedup vs baseline: 7.7607x; 1.3671x over previous
//
#include <hip/hip_runtime.h>
#include <math.h>

#define NDIM 128

// f32 pair -> packed bf16x2 (round-to-nearest-even)
__device__ __forceinline__ unsigned pack_bf16x2(float a, float b) {
    unsigned ua = __float_as_uint(a), ub = __float_as_uint(b);
    ua = (ua + 0x7FFFu + ((ua >> 16) & 1u)) >> 16;
    ub = (ub + 0x7FFFu + ((ub >> 16) & 1u)) >> 16;
    return ua | (ub << 16);
}

// ---------------------------------------------------------------------------
// K1: xt = x @ W  (f32 vector-ALU GEMM, W staged in LDS, 4x4 register tile)
//     xt stored as packed bf16; s1/s3 row-dots from f32 accumulators.
// ---------------------------------------------------------------------------
__global__ __launch_bounds__(256) void k_xt(
    const float* __restrict__ x, const float* __restrict__ W,
    const float* __restrict__ a,
    unsigned* __restrict__ xtb,   // N*64 uints (bf16x2)
    float* __restrict__ s1, float* __restrict__ s3,
    int n_nodes)
{
    __shared__ float Wl[NDIM * NDIM];   // 64 KB
    __shared__ float xr[32 * NDIM];     // 16 KB

    const int tid = threadIdx.x;
    for (int i = tid * 4; i < NDIM * NDIM; i += 256 * 4)
        *reinterpret_cast<float4*>(&Wl[i]) = *reinterpret_cast<const float4*>(&W[i]);

    const int cg = tid & 31;   // column group: cols 4*cg .. 4*cg+3
    const int rg = tid >> 5;   // row group: rows 4*rg .. 4*rg+3 within 32-row tile

    float av1[4], av3[4];
    #pragma unroll
    for (int j = 0; j < 4; ++j) {
        av1[j] = a[4 * cg + j];
        av3[j] = a[256 + 4 * cg + j];
    }

    const int ROWS = 128;
    const int rowBase = blockIdx.x * ROWS;

    for (int it = 0; it < ROWS; it += 32) {
        const int tileBase = rowBase + it;
        __syncthreads();
        for (int i = tid * 4; i < 32 * NDIM; i += 256 * 4) {
            int row = tileBase + (i >> 7);
            float4 v = make_float4(0.f, 0.f, 0.f, 0.f);
            if (row < n_nodes)
                v = *reinterpret_cast<const float4*>(&x[(size_t)row * NDIM + (i & 127)]);
            *reinterpret_cast<float4*>(&xr[i]) = v;
        }
        __syncthreads();

        float acc[4][4];
        #pragma unroll
        for (int i = 0; i < 4; ++i)
            #pragma unroll
            for (int j = 0; j < 4; ++j) acc[i][j] = 0.f;

        for (int k = 0; k < NDIM; ++k) {
            float4 wv = *reinterpret_cast<const float4*>(&Wl[k * NDIM + cg * 4]);
            #pragma unroll
            for (int i = 0; i < 4; ++i) {
                float xv = xr[(4 * rg + i) * NDIM + k];
                acc[i][0] = fmaf(xv, wv.x, acc[i][0]);
                acc[i][1] = fmaf(xv, wv.y, acc[i][1]);
                acc[i][2] = fmaf(xv, wv.z, acc[i][2]);
                acc[i][3] = fmaf(xv, wv.w, acc[i][3]);
            }
        }

        float r1[4], r3[4];
        #pragma unroll
        for (int i = 0; i < 4; ++i) {
            int row = tileBase + 4 * rg + i;
            if (row < n_nodes) {
                uint2 o;
                o.x = pack_bf16x2(acc[i][0], acc[i][1]);
                o.y = pack_bf16x2(acc[i][2], acc[i][3]);
                reinterpret_cast<uint2*>(xtb)[(size_t)row * 32 + cg] = o;
            }
            r1[i] = acc[i][0] * av1[0] + acc[i][1] * av1[1] + acc[i][2] * av1[2] + acc[i][3] * av1[3];
            r3[i] = acc[i][0] * av3[0] + acc[i][1] * av3[1] + acc[i][2] * av3[2] + acc[i][3] * av3[3];
        }
        #pragma unroll
        for (int off = 16; off; off >>= 1) {
            #pragma unroll
            for (int i = 0; i < 4; ++i) {
                r1[i] += __shfl_xor(r1[i], off);
                r3[i] += __shfl_xor(r3[i], off);
            }
        }
        if (cg == 0) {
            #pragma unroll
            for (int i = 0; i < 4; ++i) {
                int row = tileBase + 4 * rg + i;
                if (row < n_nodes) { s1[row] = r1[i]; s3[row] = r3[i]; }
            }
        }
    }
}

// ---------------------------------------------------------------------------
// K2: s2[rel] = rel_emb[rel] · (W_r @ a2)
// ---------------------------------------------------------------------------
__global__ __launch_bounds__(128) void k_rel(
    const float* __restrict__ W_r, const float* __restrict__ a,
    const float* __restrict__ rel_emb, float* __restrict__ s2)
{
    __shared__ float v[NDIM];
    const int t = threadIdx.x;
    float acc = 0.f;
    for (int c = 0; c < NDIM; ++c)
        acc = fmaf(W_r[t * NDIM + c], a[128 + c], acc);
    v[t] = acc;
    __syncthreads();
    if (t < 64) {
        float s = 0.f;
        for (int k = 0; k < NDIM; ++k)
            s = fmaf(rel_emb[t * NDIM + k], v[k], s);
        s2[t] = s;
    }
}

// ---------------------------------------------------------------------------
// K3: in-degree histogram; returned old count = edge's ordinal within node
// ---------------------------------------------------------------------------
__global__ __launch_bounds__(256) void k_count(
    const int* __restrict__ dst, int* __restrict__ deg,
    int* __restrict__ eord, int n_edges)
{
    int e = blockIdx.x * 256 + threadIdx.x;
    if (e < n_edges) eord[e] = atomicAdd(&deg[dst[e]], 1);
}

// ---------------------------------------------------------------------------
// K4a: per-block exclusive scan (1024 elems/block) + block totals
// ---------------------------------------------------------------------------
__global__ __launch_bounds__(1024) void k_scan1(
    const int* __restrict__ deg, int* __restrict__ locpre,
    int* __restrict__ btot, int n)
{
    __shared__ int sh[1024];
    const int tid = threadIdx.x;
    const int i = blockIdx.x * 1024 + tid;
    int v = (i < n) ? deg[i] : 0;
    sh[tid] = v;
    __syncthreads();
    for (int off = 1; off < 1024; off <<= 1) {
        int t = sh[tid];
        if (tid >= off) t += sh[tid - off];
        __syncthreads();
        sh[tid] = t;
        __syncthreads();
    }
    if (i < n) locpre[i] = sh[tid] - v;
    if (tid == 1023) btot[blockIdx.x] = sh[1023];
}

// K4b: exclusive scan of block totals (parallel, one block; nb <= 128)
__global__ __launch_bounds__(128) void k_scan2(int* __restrict__ bt, int nb)
{
    __shared__ int sh[128];
    const int t = threadIdx.x;
    int v = (t < nb) ? bt[t] : 0;
    sh[t] = v;
    __syncthreads();
    for (int off = 1; off < 128; off <<= 1) {
        int x = sh[t];
        if (t >= off) x += sh[t - off];
        __syncthreads();
        sh[t] = x;
        __syncthreads();
    }
    if (t < nb) bt[t] = sh[t] - v;
}

// K4c: fold block prefix into locpre -> locpre becomes absolute row start
__global__ __launch_bounds__(256) void k_fixup(
    int* __restrict__ locpre, const int* __restrict__ bpre, int n)
{
    int i = blockIdx.x * 256 + threadIdx.x;
    if (i < n) locpre[i] += bpre[i >> 10];
}

// ---------------------------------------------------------------------------
// K5: att weight + CSR placement. Record {src, w} scattered via 64-bit
//     atomicExch (16B writeback granularity vs 64B line for plain stores).
// ---------------------------------------------------------------------------
__global__ __launch_bounds__(256) void k_att_place(
    const int* __restrict__ src, const int* __restrict__ dst,
    const int* __restrict__ etype,
    const float* __restrict__ s1, const float* __restrict__ s2,
    const float* __restrict__ s3,
    const int* __restrict__ rowstart, const int* __restrict__ eord,
    unsigned long long* __restrict__ rec, int n_edges)
{
    int e = blockIdx.x * 256 + threadIdx.x;
    if (e >= n_edges) return;
    const int s = src[e];
    const int d = dst[e];
    float v = s1[s] + s2[etype[e]] + s3[d];
    v = (v >= 0.f) ? v : 0.2f * v;
    const float w = expf(v);
    const int pos = rowstart[d] + eord[e];
    unsigned long long pk =
        ((unsigned long long)__float_as_uint(w) << 32) | (unsigned)s;
    atomicExch(&rec[pos], pk);
}

// ---------------------------------------------------------------------------
// K6: gather-reduce. One 64-lane wave per node; lane owns 2 cols (bf16x2).
//     wsum re-derived from records (every lane sees w via broadcast load).
// ---------------------------------------------------------------------------
__global__ __launch_bounds__(256) void k_gather(
    const unsigned* __restrict__ xtu, const unsigned long long* __restrict__ rec,
    const int* __restrict__ deg, const int* __restrict__ rowstart,
    float* __restrict__ out, int n_nodes)
{
    const int n = blockIdx.x * 4 + (threadIdx.x >> 6);
    if (n >= n_nodes) return;
    const int lane = threadIdx.x & 63;
    const int start = __builtin_amdgcn_readfirstlane(rowstart[n]);
    const int cnt   = __builtin_amdgcn_readfirstlane(deg[n]);

    float2 acc = make_float2(0.f, 0.f);
    float wsum = 0.f;
    int i = 0;
    for (; i + 2 <= cnt; i += 2) {
        unsigned long long r0 = rec[start + i];
        unsigned long long r1 = rec[start + i + 1];
        unsigned p0 = xtu[(size_t)(unsigned)(r0 & 0xFFFFFFFFu) * 64 + lane];
        unsigned p1 = xtu[(size_t)(unsigned)(r1 & 0xFFFFFFFFu) * 64 + lane];
        float w0 = __uint_as_float((unsigned)(r0 >> 32));
        float w1 = __uint_as_float((unsigned)(r1 >> 32));
        wsum += w0 + w1;
        acc.x = fmaf(w0, __uint_as_float(p0 << 16), acc.x);
        acc.y = fmaf(w0, __uint_as_float(p0 & 0xFFFF0000u), acc.y);
        acc.x = fmaf(w1, __uint_as_float(p1 << 16), acc.x);
        acc.y = fmaf(w1, __uint_as_float(p1 & 0xFFFF0000u), acc.y);
    }
    if (i < cnt) {
        unsigned long long r = rec[start + i];
        unsigned p = xtu[(size_t)(unsigned)(r & 0xFFFFFFFFu) * 64 + lane];
        float w = __uint_as_float((unsigned)(r >> 32));
        wsum += w;
        acc.x = fmaf(w, __uint_as_float(p << 16), acc.x);
        acc.y = fmaf(w, __uint_as_float(p & 0xFFFF0000u), acc.y);
    }
    const float inv = 1.0f / (wsum + 1e-10f);
    reinterpret_cast<float2*>(out)[(size_t)n * 64 + lane] =
        make_float2(acc.x * inv, acc.y * inv);
}

extern "C" void kernel_launch(void* const* d_in, const int* in_sizes, int n_in,
                              void* d_out, int out_size, void* d_ws, size_t ws_size,
                              hipStream_t stream)
{
    const float* x    = (const float*)d_in[0];
    const int*   ei   = (const int*)d_in[1];   // [2,E]: src row then dst row
    const int*   et   = (const int*)d_in[2];
    const float* W    = (const float*)d_in[3];
    const float* W_r  = (const float*)d_in[4];
    const float* a    = (const float*)d_in[5];
    const float* rel  = (const float*)d_in[6];
    float* out = (float*)d_out;

    const int E  = in_sizes[2];
    const int N  = in_sizes[0] / NDIM;
    const int NB = (N + 1023) / 1024;           // 98 for N=100K (<=128 req'd by k_scan2)

    char* p = (char*)d_ws;
    unsigned* xtb   = (unsigned*)p;             p += (size_t)N * 64 * 4;  // bf16x2
    float* s1       = (float*)p;                p += (size_t)N * 4;
    float* s3       = (float*)p;                p += (size_t)N * 4;
    float* s2       = (float*)p;                p += 64 * 4;
    int* deg        = (int*)p;                  p += (size_t)N * 4;
    int* locpre     = (int*)p;                  p += (size_t)N * 4;
    int* btot       = (int*)p;                  p += 128 * 4;
    int* eord       = (int*)p;                  p += (size_t)E * 4;
    unsigned long long* rec = (unsigned long long*)p;   // E * 8B

    const int* srcArr = ei;
    const int* dstArr = ei + E;

    hipMemsetAsync(deg, 0, (size_t)N * sizeof(int), stream);

    k_xt<<<(N + 127) / 128, 256, 0, stream>>>(x, W, a, xtb, s1, s3, N);
    k_rel<<<1, 128, 0, stream>>>(W_r, a, rel, s2);
    k_count<<<(E + 255) / 256, 256, 0, stream>>>(dstArr, deg, eord, E);
    k_scan1<<<NB, 1024, 0, stream>>>(deg, locpre, btot, N);
    k_scan2<<<1, 128, 0, stream>>>(btot, NB);
    k_fixup<<<(N + 255) / 256, 256, 0, stream>>>(locpre, btot, N);
    k_att_place<<<(E + 255) / 256, 256, 0, stream>>>(
        srcArr, dstArr, et, s1, s2, s3, locpre, eord, rec, E);
    k_gather<<<(N + 3) / 4, 256, 0, stream>>>(
        xtb, rec, deg, locpre, out, N);
}

// Round 4
// 194.572 us; speedup vs baseline: 9.4852x; 1.2222x over previous
//
#include <hip/hip_runtime.h>
#include <math.h>

#define NDIM 128

typedef __bf16 bf16x8 __attribute__((ext_vector_type(8)));
typedef float  f32x4  __attribute__((ext_vector_type(4)));

// f32 pair -> packed bf16x2 (round-to-nearest-even)
__device__ __forceinline__ unsigned pack_bf16x2(float a, float b) {
    unsigned ua = __float_as_uint(a), ub = __float_as_uint(b);
    ua = (ua + 0x7FFFu + ((ua >> 16) & 1u)) >> 16;
    ub = (ub + 0x7FFFu + ((ub >> 16) & 1u)) >> 16;
    return ua | (ub << 16);
}

// ---------------------------------------------------------------------------
// K0: prep. block 0: W[k][n] f32 -> Wt[n][k] bf16 (global).
//           block 1: s2[rel] = rel_emb[rel] · (W_r @ a2)
// ---------------------------------------------------------------------------
__global__ __launch_bounds__(256) void k_prep(
    const float* __restrict__ W, const float* __restrict__ W_r,
    const float* __restrict__ a, const float* __restrict__ rel_emb,
    unsigned short* __restrict__ Wt, float* __restrict__ s2)
{
    if (blockIdx.x == 0) {
        for (int i = threadIdx.x; i < NDIM * NDIM; i += 256) {
            int n = i & 127, k = i >> 7;             // consecutive tid -> consecutive n (coalesced read)
            float v = W[k * NDIM + n];
            Wt[n * NDIM + k] = (unsigned short)(pack_bf16x2(v, 0.f) & 0xFFFFu);
        }
    } else {
        __shared__ float vsh[NDIM];
        const int t = threadIdx.x;
        if (t < 128) {
            float acc = 0.f;
            for (int c = 0; c < NDIM; ++c)
                acc = fmaf(W_r[t * NDIM + c], a[128 + c], acc);
            vsh[t] = acc;
        }
        __syncthreads();
        if (t < 64) {
            float s = 0.f;
            for (int k = 0; k < NDIM; ++k)
                s = fmaf(rel_emb[t * NDIM + k], vsh[k], s);
            s2[t] = s;
        }
    }
}

// ---------------------------------------------------------------------------
// K1: xt = x @ W via mfma_f32_16x16x32_bf16. 128 rows/block, 4 waves,
//     wave owns 32 rows x 128 cols (2x8 fragments). LDS XOR-swizzled (T2).
//     s1/s3 row-dots from f32 accumulators; xt stored bf16 via LDS restage.
// ---------------------------------------------------------------------------
__global__ __launch_bounds__(256) void k_xt(
    const float* __restrict__ x, const unsigned short* __restrict__ Wt,
    const float* __restrict__ a,
    unsigned* __restrict__ xtb,   // N*64 uints (bf16x2)
    float* __restrict__ s1, float* __restrict__ s3,
    int n_nodes)
{
    __shared__ __align__(16) unsigned short WL[NDIM * NDIM]; // [n][k] bf16 swz, 32 KB
    __shared__ __align__(16) unsigned short XL[NDIM * NDIM]; // [m][k] bf16 swz, 32 KB (reused for out)
    const int tid  = threadIdx.x;
    const int lane = tid & 63;
    const int wave = tid >> 6;
    const int l15  = lane & 15;
    const int l4   = lane >> 4;
    char* wb = (char*)WL;
    char* xb = (char*)XL;

    // stage Wt (already bf16 [n][k]) -> WL swizzled, 16B chunks, conflict-free
    for (int i = tid * 8; i < NDIM * NDIM; i += 256 * 8) {
        int n = i >> 7, k = i & 127;
        uint4 v = *reinterpret_cast<const uint4*>(Wt + i);
        *reinterpret_cast<uint4*>(wb + ((n * 256 + k * 2) ^ ((n & 7) << 4))) = v;
    }

    const int rowBase = blockIdx.x * 128;
    // stage x tile f32 -> XL bf16 swizzled (8B writes, within-slot safe)
    for (int i = tid * 4; i < NDIM * NDIM; i += 256 * 4) {
        int r = i >> 7, k = i & 127;
        float4 v = make_float4(0.f, 0.f, 0.f, 0.f);
        if (rowBase + r < n_nodes)
            v = *reinterpret_cast<const float4*>(&x[(size_t)(rowBase + r) * NDIM + k]);
        uint2 p = make_uint2(pack_bf16x2(v.x, v.y), pack_bf16x2(v.z, v.w));
        *reinterpret_cast<uint2*>(xb + ((r * 256 + k * 2) ^ ((r & 7) << 4))) = p;
    }
    __syncthreads();

    f32x4 acc[2][8];
    #pragma unroll
    for (int i = 0; i < 2; ++i)
        #pragma unroll
        for (int j = 0; j < 8; ++j) acc[i][j] = (f32x4){0.f, 0.f, 0.f, 0.f};

    #pragma unroll
    for (int kt = 0; kt < 4; ++kt) {
        const int kb2 = (kt * 32 + l4 * 8) * 2;   // byte offset of this lane's k-slice
        bf16x8 af[2], bf[8];
        #pragma unroll
        for (int rf = 0; rf < 2; ++rf) {
            int r = wave * 32 + rf * 16 + l15;    // A: row = lane&15
            af[rf] = *reinterpret_cast<bf16x8*>(xb + ((r * 256 + kb2) ^ ((r & 7) << 4)));
        }
        #pragma unroll
        for (int cf = 0; cf < 8; ++cf) {
            int n = cf * 16 + l15;                // B: col = lane&15
            bf[cf] = *reinterpret_cast<bf16x8*>(wb + ((n * 256 + kb2) ^ ((n & 7) << 4)));
        }
        #pragma unroll
        for (int rf = 0; rf < 2; ++rf)
            #pragma unroll
            for (int cf = 0; cf < 8; ++cf)
                acc[rf][cf] = __builtin_amdgcn_mfma_f32_16x16x32_bf16(
                    af[rf], bf[cf], acc[rf][cf], 0, 0, 0);
    }

    // s1/s3: C/D layout col=lane&15, row=(lane>>4)*4+reg  [m89]
    float av1[8], av3[8];
    #pragma unroll
    for (int cf = 0; cf < 8; ++cf) {
        av1[cf] = a[cf * 16 + l15];
        av3[cf] = a[256 + cf * 16 + l15];
    }
    #pragma unroll
    for (int rf = 0; rf < 2; ++rf) {
        #pragma unroll
        for (int reg = 0; reg < 4; ++reg) {
            float p1 = 0.f, p3 = 0.f;
            #pragma unroll
            for (int cf = 0; cf < 8; ++cf) {
                p1 = fmaf(acc[rf][cf][reg], av1[cf], p1);
                p3 = fmaf(acc[rf][cf][reg], av3[cf], p3);
            }
            #pragma unroll
            for (int off = 8; off; off >>= 1) {
                p1 += __shfl_xor(p1, off);
                p3 += __shfl_xor(p3, off);
            }
            if (l15 == 0) {
                int r = rowBase + wave * 32 + rf * 16 + l4 * 4 + reg;
                if (r < n_nodes) { s1[r] = p1; s3[r] = p3; }
            }
        }
    }

    // restage accumulators (bf16) into XL, then coalesced global write
    __syncthreads();
    #pragma unroll
    for (int rf = 0; rf < 2; ++rf)
        #pragma unroll
        for (int cf = 0; cf < 8; ++cf)
            #pragma unroll
            for (int reg = 0; reg < 4; ++reg) {
                int r = wave * 32 + rf * 16 + l4 * 4 + reg;
                int c = cf * 16 + l15;
                *reinterpret_cast<unsigned short*>(xb + ((r * 256 + c * 2) ^ ((r & 7) << 4))) =
                    (unsigned short)(pack_bf16x2(acc[rf][cf][reg], 0.f) & 0xFFFFu);
            }
    __syncthreads();
    for (int i = tid * 8; i < NDIM * NDIM; i += 256 * 8) {
        int r = i >> 7, k = i & 127;
        if (rowBase + r < n_nodes) {
            uint4 v = *reinterpret_cast<uint4*>(xb + ((r * 256 + k * 2) ^ ((r & 7) << 4)));
            *reinterpret_cast<uint4*>(&xtb[(size_t)(rowBase + r) * 64 + (k >> 1)]) = v;
        }
    }
}

// ---------------------------------------------------------------------------
// K3: in-degree histogram; returned old count = edge's ordinal within node
// ---------------------------------------------------------------------------
__global__ __launch_bounds__(256) void k_count(
    const int* __restrict__ dst, int* __restrict__ deg,
    int* __restrict__ eord, int n_edges)
{
    int e = blockIdx.x * 256 + threadIdx.x;
    if (e < n_edges) eord[e] = atomicAdd(&deg[dst[e]], 1);
}

// ---------------------------------------------------------------------------
// K4a: per-block exclusive scan (1024 elems/block) + block totals
// ---------------------------------------------------------------------------
__global__ __launch_bounds__(1024) void k_scan1(
    const int* __restrict__ deg, int* __restrict__ locpre,
    int* __restrict__ btot, int n)
{
    __shared__ int sh[1024];
    const int tid = threadIdx.x;
    const int i = blockIdx.x * 1024 + tid;
    int v = (i < n) ? deg[i] : 0;
    sh[tid] = v;
    __syncthreads();
    for (int off = 1; off < 1024; off <<= 1) {
        int t = sh[tid];
        if (tid >= off) t += sh[tid - off];
        __syncthreads();
        sh[tid] = t;
        __syncthreads();
    }
    if (i < n) locpre[i] = sh[tid] - v;
    if (tid == 1023) btot[blockIdx.x] = sh[1023];
}

// K4b: exclusive scan of block totals (parallel, one block; nb <= 128)
__global__ __launch_bounds__(128) void k_scan2(int* __restrict__ bt, int nb)
{
    __shared__ int sh[128];
    const int t = threadIdx.x;
    int v = (t < nb) ? bt[t] : 0;
    sh[t] = v;
    __syncthreads();
    for (int off = 1; off < 128; off <<= 1) {
        int x = sh[t];
        if (t >= off) x += sh[t - off];
        __syncthreads();
        sh[t] = x;
        __syncthreads();
    }
    if (t < nb) bt[t] = sh[t] - v;
}

// ---------------------------------------------------------------------------
// K5: att weight + CSR placement via 64-bit atomicExch (16B writeback
//     granularity vs 64B line for plain scattered stores).
// ---------------------------------------------------------------------------
__global__ __launch_bounds__(256) void k_att_place(
    const int* __restrict__ src, const int* __restrict__ dst,
    const int* __restrict__ etype,
    const float* __restrict__ s1, const float* __restrict__ s2,
    const float* __restrict__ s3,
    const int* __restrict__ locpre, const int* __restrict__ bpre,
    const int* __restrict__ eord,
    unsigned long long* __restrict__ rec, int n_edges)
{
    int e = blockIdx.x * 256 + threadIdx.x;
    if (e >= n_edges) return;
    const int s = src[e];
    const int d = dst[e];
    float v = s1[s] + s2[etype[e]] + s3[d];
    v = (v >= 0.f) ? v : 0.2f * v;
    const float w = expf(v);
    const int pos = locpre[d] + bpre[d >> 10] + eord[e];
    unsigned long long pk =
        ((unsigned long long)__float_as_uint(w) << 32) | (unsigned)s;
    atomicExch(&rec[pos], pk);
}

// ---------------------------------------------------------------------------
// K6: gather-reduce. One 64-lane wave per node; lane owns 2 cols (bf16x2).
//     wsum re-derived from records (broadcast loads).
// ---------------------------------------------------------------------------
__global__ __launch_bounds__(256) void k_gather(
    const unsigned* __restrict__ xtu, const unsigned long long* __restrict__ rec,
    const int* __restrict__ deg, const int* __restrict__ locpre,
    const int* __restrict__ bpre,
    float* __restrict__ out, int n_nodes)
{
    const int n = blockIdx.x * 4 + (threadIdx.x >> 6);
    if (n >= n_nodes) return;
    const int lane = threadIdx.x & 63;
    const int start = __builtin_amdgcn_readfirstlane(locpre[n] + bpre[n >> 10]);
    const int cnt   = __builtin_amdgcn_readfirstlane(deg[n]);

    float2 acc = make_float2(0.f, 0.f);
    float wsum = 0.f;
    int i = 0;
    for (; i + 2 <= cnt; i += 2) {
        unsigned long long r0 = rec[start + i];
        unsigned long long r1 = rec[start + i + 1];
        unsigned p0 = xtu[(size_t)(unsigned)(r0 & 0xFFFFFFFFu) * 64 + lane];
        unsigned p1 = xtu[(size_t)(unsigned)(r1 & 0xFFFFFFFFu) * 64 + lane];
        float w0 = __uint_as_float((unsigned)(r0 >> 32));
        float w1 = __uint_as_float((unsigned)(r1 >> 32));
        wsum += w0 + w1;
        acc.x = fmaf(w0, __uint_as_float(p0 << 16), acc.x);
        acc.y = fmaf(w0, __uint_as_float(p0 & 0xFFFF0000u), acc.y);
        acc.x = fmaf(w1, __uint_as_float(p1 << 16), acc.x);
        acc.y = fmaf(w1, __uint_as_float(p1 & 0xFFFF0000u), acc.y);
    }
    if (i < cnt) {
        unsigned long long r = rec[start + i];
        unsigned p = xtu[(size_t)(unsigned)(r & 0xFFFFFFFFu) * 64 + lane];
        float w = __uint_as_float((unsigned)(r >> 32));
        wsum += w;
        acc.x = fmaf(w, __uint_as_float(p << 16), acc.x);
        acc.y = fmaf(w, __uint_as_float(p & 0xFFFF0000u), acc.y);
    }
    const float inv = 1.0f / (wsum + 1e-10f);
    reinterpret_cast<float2*>(out)[(size_t)n * 64 + lane] =
        make_float2(acc.x * inv, acc.y * inv);
}

extern "C" void kernel_launch(void* const* d_in, const int* in_sizes, int n_in,
                              void* d_out, int out_size, void* d_ws, size_t ws_size,
                              hipStream_t stream)
{
    const float* x    = (const float*)d_in[0];
    const int*   ei   = (const int*)d_in[1];   // [2,E]: src row then dst row
    const int*   et   = (const int*)d_in[2];
    const float* W    = (const float*)d_in[3];
    const float* W_r  = (const float*)d_in[4];
    const float* a    = (const float*)d_in[5];
    const float* rel  = (const float*)d_in[6];
    float* out = (float*)d_out;

    const int E  = in_sizes[2];
    const int N  = in_sizes[0] / NDIM;
    const int NB = (N + 1023) / 1024;           // 98 (<=128 req'd by k_scan2)

    char* p = (char*)d_ws;
    unsigned* xtb        = (unsigned*)p;        p += (size_t)N * 64 * 4;   // bf16x2
    unsigned short* Wt   = (unsigned short*)p;  p += NDIM * NDIM * 2;      // 32 KB
    float* s1            = (float*)p;           p += (size_t)N * 4;
    float* s3            = (float*)p;           p += (size_t)N * 4;
    float* s2            = (float*)p;           p += 64 * 4;
    int* deg             = (int*)p;             p += (size_t)N * 4;
    int* locpre          = (int*)p;             p += (size_t)N * 4;
    int* btot            = (int*)p;             p += 128 * 4;
    int* eord            = (int*)p;             p += (size_t)E * 4;
    unsigned long long* rec = (unsigned long long*)p;   // E * 8B

    const int* srcArr = ei;
    const int* dstArr = ei + E;

    hipMemsetAsync(deg, 0, (size_t)N * sizeof(int), stream);

    k_prep<<<2, 256, 0, stream>>>(W, W_r, a, rel, Wt, s2);
    k_xt<<<(N + 127) / 128, 256, 0, stream>>>(x, Wt, a, xtb, s1, s3, N);
    k_count<<<(E + 255) / 256, 256, 0, stream>>>(dstArr, deg, eord, E);
    k_scan1<<<NB, 1024, 0, stream>>>(deg, locpre, btot, N);
    k_scan2<<<1, 128, 0, stream>>>(btot, NB);
    k_att_place<<<(E + 255) / 256, 256, 0, stream>>>(
        srcArr, dstArr, et, s1, s2, s3, locpre, btot, eord, rec, E);
    k_gather<<<(N + 3) / 4, 256, 0, stream>>>(
        xtb, rec, deg, locpre, btot, out, N);
}